// Round 1
// baseline (136.971 us; speedup 1.0000x reference)
//
#include <hip/hip_runtime.h>

#define SMOOTH 1e-5

// One streaming pass producing 4 accumulators in d_ws (doubles):
//   acc[0] = c1  (count of t==1)
//   acc[1] = s1  (sum p where t==1)
//   acc[2] = q0  (sum p^2 where t==0)
//   acc[3] = q1  (sum p^2 where t==1)
__global__ __launch_bounds__(256) void balanced_loss_main(
    const float* __restrict__ in, const int* __restrict__ tg,
    long long n, double* __restrict__ acc)
{
    const long long nvec = n >> 2;  // float4 chunks
    float lc1 = 0.f, ls1 = 0.f, lq0 = 0.f, lq1 = 0.f;

    const long long tid    = (long long)blockIdx.x * blockDim.x + threadIdx.x;
    const long long stride = (long long)gridDim.x * blockDim.x;
    const float4* __restrict__ in4 = (const float4*)in;
    const int4*  __restrict__ tg4 = (const int4*)tg;

#define PROC(xv, tv)                                        \
    {                                                       \
        float p  = 1.f / (1.f + __expf(-(xv)));             \
        float pp = p * p;                                   \
        float ft = (tv) ? 1.f : 0.f;                        \
        lc1 += ft;                                          \
        ls1 += ft * p;                                      \
        lq1 += ft * pp;                                     \
        lq0 += (1.f - ft) * pp;                             \
    }

    for (long long i = tid; i < nvec; i += stride) {
        float4 x = in4[i];
        int4   t = tg4[i];
        PROC(x.x, t.x);
        PROC(x.y, t.y);
        PROC(x.z, t.z);
        PROC(x.w, t.w);
    }

    // scalar tail (n not divisible by 4) — block 0 only
    const long long tail0 = nvec << 2;
    if (blockIdx.x == 0) {
        for (long long i = tail0 + threadIdx.x; i < n; i += blockDim.x) {
            float x = in[i];
            int   t = tg[i];
            PROC(x, t);
        }
    }
#undef PROC

    // wave-64 reduction in double
    double dc1 = (double)lc1, ds1 = (double)ls1;
    double dq0 = (double)lq0, dq1 = (double)lq1;
    for (int off = 32; off > 0; off >>= 1) {
        dc1 += __shfl_down(dc1, off, 64);
        ds1 += __shfl_down(ds1, off, 64);
        dq0 += __shfl_down(dq0, off, 64);
        dq1 += __shfl_down(dq1, off, 64);
    }

    __shared__ double sm[4][4];  // [wave][acc]
    const int wid  = threadIdx.x >> 6;
    const int lane = threadIdx.x & 63;
    if (lane == 0) {
        sm[wid][0] = dc1; sm[wid][1] = ds1;
        sm[wid][2] = dq0; sm[wid][3] = dq1;
    }
    __syncthreads();
    if (threadIdx.x == 0) {
        double a0 = 0, a1 = 0, a2 = 0, a3 = 0;
        for (int w = 0; w < 4; ++w) {
            a0 += sm[w][0]; a1 += sm[w][1];
            a2 += sm[w][2]; a3 += sm[w][3];
        }
        atomicAdd(&acc[0], a0);
        atomicAdd(&acc[1], a1);
        atomicAdd(&acc[2], a2);
        atomicAdd(&acc[3], a3);
    }
}

__global__ void balanced_loss_final(const double* __restrict__ acc,
                                    float* __restrict__ out, long long n)
{
    double c1 = acc[0];
    double c0 = (double)n - c1;
    double w0 = 1.0 / ((c0 + SMOOTH) * (c0 + SMOOTH));
    double w1 = 1.0 / ((c1 + SMOOTH) * (c1 + SMOOTH));
    double I  = w1 * acc[1];
    double D  = w0 * acc[2] + w1 * (acc[3] + c1);  // sum(t*t) over t==1 is c1
    out[0] = (float)(1.0 - (2.0 * I + SMOOTH) / (D + SMOOTH));
}

extern "C" void kernel_launch(void* const* d_in, const int* in_sizes, int n_in,
                              void* d_out, int out_size, void* d_ws, size_t ws_size,
                              hipStream_t stream) {
    const float* in = (const float*)d_in[0];
    const int*   tg = (const int*)d_in[1];
    long long n = (long long)in_sizes[0];
    double* acc = (double*)d_ws;

    hipMemsetAsync(acc, 0, 4 * sizeof(double), stream);

    const int block = 256;
    const int grid  = 2048;  // 8 blocks/CU; grid-stride covers the rest
    balanced_loss_main<<<grid, block, 0, stream>>>(in, tg, n, acc);
    balanced_loss_final<<<1, 1, 0, stream>>>(acc, (float*)d_out, n);
}

// Round 2
// 52.232 us; speedup vs baseline: 2.6224x; 2.6224x over previous
//
#include <hip/hip_runtime.h>

#define SMOOTH 1e-5

// Stage 1: streaming pass. Each block writes 4 double partials to ws[4*bid..]:
//   [0] c1 (count t==1), [1] s1 (sum p | t==1), [2] q0 (sum p^2 | t==0), [3] q1 (sum p^2 | t==1)
__global__ __launch_bounds__(256) void balanced_loss_stage1(
    const float* __restrict__ in, const int* __restrict__ tg,
    long long n, double* __restrict__ ws)
{
    const long long nvec = n >> 2;  // float4 chunks
    float lc1 = 0.f, ls1 = 0.f, lq0 = 0.f, lq1 = 0.f;

    const long long tid    = (long long)blockIdx.x * blockDim.x + threadIdx.x;
    const long long stride = (long long)gridDim.x * blockDim.x;
    const float4* __restrict__ in4 = (const float4*)in;
    const int4*  __restrict__ tg4 = (const int4*)tg;

#define PROC(xv, tv)                                        \
    {                                                       \
        float e  = __expf(-(xv));                           \
        float p  = __fdividef(1.f, 1.f + e);                \
        float pp = p * p;                                   \
        float ft = (tv) ? 1.f : 0.f;                        \
        lc1 += ft;                                          \
        ls1 += ft * p;                                      \
        lq1 += ft * pp;                                     \
        lq0 += (1.f - ft) * pp;                             \
    }

    long long i = tid;
    // main loop unrolled x4: 8 independent 16B loads in flight per wave
    for (; i + 3 * stride < nvec; i += 4 * stride) {
        float4 x0 = in4[i];
        float4 x1 = in4[i + stride];
        float4 x2 = in4[i + 2 * stride];
        float4 x3 = in4[i + 3 * stride];
        int4   t0 = tg4[i];
        int4   t1 = tg4[i + stride];
        int4   t2 = tg4[i + 2 * stride];
        int4   t3 = tg4[i + 3 * stride];
        PROC(x0.x, t0.x); PROC(x0.y, t0.y); PROC(x0.z, t0.z); PROC(x0.w, t0.w);
        PROC(x1.x, t1.x); PROC(x1.y, t1.y); PROC(x1.z, t1.z); PROC(x1.w, t1.w);
        PROC(x2.x, t2.x); PROC(x2.y, t2.y); PROC(x2.z, t2.z); PROC(x2.w, t2.w);
        PROC(x3.x, t3.x); PROC(x3.y, t3.y); PROC(x3.z, t3.z); PROC(x3.w, t3.w);
    }
    for (; i < nvec; i += stride) {
        float4 x = in4[i];
        int4   t = tg4[i];
        PROC(x.x, t.x); PROC(x.y, t.y); PROC(x.z, t.z); PROC(x.w, t.w);
    }

    // scalar tail (n not divisible by 4) — block 0 only
    const long long tail0 = nvec << 2;
    if (blockIdx.x == 0) {
        for (long long j = tail0 + threadIdx.x; j < n; j += blockDim.x) {
            float x = in[j];
            int   t = tg[j];
            PROC(x, t);
        }
    }
#undef PROC

    // wave-64 reduction in double
    double dc1 = (double)lc1, ds1 = (double)ls1;
    double dq0 = (double)lq0, dq1 = (double)lq1;
    for (int off = 32; off > 0; off >>= 1) {
        dc1 += __shfl_down(dc1, off, 64);
        ds1 += __shfl_down(ds1, off, 64);
        dq0 += __shfl_down(dq0, off, 64);
        dq1 += __shfl_down(dq1, off, 64);
    }

    __shared__ double sm[4][4];  // [wave][acc]
    const int wid  = threadIdx.x >> 6;
    const int lane = threadIdx.x & 63;
    if (lane == 0) {
        sm[wid][0] = dc1; sm[wid][1] = ds1;
        sm[wid][2] = dq0; sm[wid][3] = dq1;
    }
    __syncthreads();
    if (threadIdx.x == 0) {
        double a0 = 0, a1 = 0, a2 = 0, a3 = 0;
        for (int w = 0; w < 4; ++w) {
            a0 += sm[w][0]; a1 += sm[w][1];
            a2 += sm[w][2]; a3 += sm[w][3];
        }
        double* p = ws + (size_t)blockIdx.x * 4;
        p[0] = a0; p[1] = a1; p[2] = a2; p[3] = a3;  // plain stores, no atomics
    }
}

// Stage 2: one block reduces nblocks*4 doubles and writes the loss.
__global__ __launch_bounds__(256) void balanced_loss_stage2(
    const double* __restrict__ ws, int nblocks,
    float* __restrict__ out, long long n)
{
    double c1 = 0, s1 = 0, q0 = 0, q1 = 0;
    for (int b = threadIdx.x; b < nblocks; b += blockDim.x) {
        const double* p = ws + (size_t)b * 4;
        c1 += p[0]; s1 += p[1]; q0 += p[2]; q1 += p[3];
    }
    for (int off = 32; off > 0; off >>= 1) {
        c1 += __shfl_down(c1, off, 64);
        s1 += __shfl_down(s1, off, 64);
        q0 += __shfl_down(q0, off, 64);
        q1 += __shfl_down(q1, off, 64);
    }
    __shared__ double sm[4][4];
    const int wid  = threadIdx.x >> 6;
    const int lane = threadIdx.x & 63;
    if (lane == 0) {
        sm[wid][0] = c1; sm[wid][1] = s1;
        sm[wid][2] = q0; sm[wid][3] = q1;
    }
    __syncthreads();
    if (threadIdx.x == 0) {
        double a0 = 0, a1 = 0, a2 = 0, a3 = 0;
        for (int w = 0; w < 4; ++w) {
            a0 += sm[w][0]; a1 += sm[w][1];
            a2 += sm[w][2]; a3 += sm[w][3];
        }
        double cc1 = a0;
        double cc0 = (double)n - cc1;
        double w0 = 1.0 / ((cc0 + SMOOTH) * (cc0 + SMOOTH));
        double w1 = 1.0 / ((cc1 + SMOOTH) * (cc1 + SMOOTH));
        double I  = w1 * a1;
        double D  = w0 * a2 + w1 * (a3 + cc1);  // sum(t*t | t==1) == c1
        out[0] = (float)(1.0 - (2.0 * I + SMOOTH) / (D + SMOOTH));
    }
}

extern "C" void kernel_launch(void* const* d_in, const int* in_sizes, int n_in,
                              void* d_out, int out_size, void* d_ws, size_t ws_size,
                              hipStream_t stream) {
    const float* in = (const float*)d_in[0];
    const int*   tg = (const int*)d_in[1];
    long long n = (long long)in_sizes[0];
    double* ws = (double*)d_ws;

    const int block = 256;
    const int grid  = 2048;  // 8 blocks/CU; 64 KB of partials in d_ws

    balanced_loss_stage1<<<grid, block, 0, stream>>>(in, tg, n, ws);
    balanced_loss_stage2<<<1, block, 0, stream>>>(ws, grid, (float*)d_out, n);
}

// Round 3
// 51.067 us; speedup vs baseline: 2.6822x; 1.0228x over previous
//
#include <hip/hip_runtime.h>

#define SMOOTH 1e-5

typedef float f32x4 __attribute__((ext_vector_type(4)));
typedef int   i32x4 __attribute__((ext_vector_type(4)));

__device__ __forceinline__ f32x4 ldnt(const f32x4* p) {
    return __builtin_nontemporal_load(p);   // nt: don't allocate in L3 (float stream)
}

// Stage 1: streaming pass. Each block writes 4 double partials to ws[4*bid..]:
//   [0] c1 (count t==1), [1] s1 (sum p | t==1), [2] qa (sum p^2, all), [3] q1 (sum p^2 | t==1)
__global__ __launch_bounds__(256, 8) void balanced_loss_stage1(
    const float* __restrict__ in, const int* __restrict__ tg,
    long long n, double* __restrict__ ws)
{
    const long long nvec = n >> 2;  // float4 chunks
    float lc1 = 0.f, ls1 = 0.f, lqa = 0.f, lq1 = 0.f;

    const long long tid    = (long long)blockIdx.x * blockDim.x + threadIdx.x;
    const long long stride = (long long)gridDim.x * blockDim.x;
    const f32x4* __restrict__ in4 = (const f32x4*)in;
    const i32x4* __restrict__ tg4 = (const i32x4*)tg;

#define PROC(xv, tv)                                        \
    {                                                       \
        float e  = __expf(-(xv));                           \
        float p  = __builtin_amdgcn_rcpf(1.f + e);          \
        float pp = p * p;                                   \
        float ft = (float)(tv);  /* t in {0,1} */           \
        lqa += pp;                                          \
        lc1 += ft;                                          \
        ls1 += ft * p;                                      \
        lq1 += ft * pp;                                     \
    }

    long long i = tid;
    // unroll x4, loads interleaved (x,t pairs) and clustered ahead of compute
    for (; i + 3 * stride < nvec; i += 4 * stride) {
        f32x4 x0 = ldnt(in4 + i);
        i32x4 t0 = tg4[i];
        f32x4 x1 = ldnt(in4 + i + stride);
        i32x4 t1 = tg4[i + stride];
        f32x4 x2 = ldnt(in4 + i + 2 * stride);
        i32x4 t2 = tg4[i + 2 * stride];
        f32x4 x3 = ldnt(in4 + i + 3 * stride);
        i32x4 t3 = tg4[i + 3 * stride];
        __builtin_amdgcn_sched_barrier(0);  // keep the 8-load cluster ahead of compute
        PROC(x0.x, t0.x); PROC(x0.y, t0.y); PROC(x0.z, t0.z); PROC(x0.w, t0.w);
        PROC(x1.x, t1.x); PROC(x1.y, t1.y); PROC(x1.z, t1.z); PROC(x1.w, t1.w);
        PROC(x2.x, t2.x); PROC(x2.y, t2.y); PROC(x2.z, t2.z); PROC(x2.w, t2.w);
        PROC(x3.x, t3.x); PROC(x3.y, t3.y); PROC(x3.z, t3.z); PROC(x3.w, t3.w);
    }
    for (; i < nvec; i += stride) {
        f32x4 x = ldnt(in4 + i);
        i32x4 t = tg4[i];
        PROC(x.x, t.x); PROC(x.y, t.y); PROC(x.z, t.z); PROC(x.w, t.w);
    }

    // scalar tail (n not divisible by 4) — block 0 only
    const long long tail0 = nvec << 2;
    if (blockIdx.x == 0) {
        for (long long j = tail0 + threadIdx.x; j < n; j += blockDim.x) {
            float x = in[j];
            int   t = tg[j];
            PROC(x, t);
        }
    }
#undef PROC

    // wave-64 reduction in double
    double dc1 = (double)lc1, ds1 = (double)ls1;
    double dqa = (double)lqa, dq1 = (double)lq1;
    for (int off = 32; off > 0; off >>= 1) {
        dc1 += __shfl_down(dc1, off, 64);
        ds1 += __shfl_down(ds1, off, 64);
        dqa += __shfl_down(dqa, off, 64);
        dq1 += __shfl_down(dq1, off, 64);
    }

    __shared__ double sm[4][4];  // [wave][acc]
    const int wid  = threadIdx.x >> 6;
    const int lane = threadIdx.x & 63;
    if (lane == 0) {
        sm[wid][0] = dc1; sm[wid][1] = ds1;
        sm[wid][2] = dqa; sm[wid][3] = dq1;
    }
    __syncthreads();
    if (threadIdx.x == 0) {
        double a0 = 0, a1 = 0, a2 = 0, a3 = 0;
        for (int w = 0; w < 4; ++w) {
            a0 += sm[w][0]; a1 += sm[w][1];
            a2 += sm[w][2]; a3 += sm[w][3];
        }
        double* p = ws + (size_t)blockIdx.x * 4;
        p[0] = a0; p[1] = a1; p[2] = a2; p[3] = a3;  // plain stores, no atomics
    }
}

// Stage 2: one 1024-thread block reduces nblocks*4 doubles and writes the loss.
__global__ __launch_bounds__(1024) void balanced_loss_stage2(
    const double* __restrict__ ws, int nblocks,
    float* __restrict__ out, long long n)
{
    double c1 = 0, s1 = 0, qa = 0, q1 = 0;
    for (int b = threadIdx.x; b < nblocks; b += blockDim.x) {
        const double* p = ws + (size_t)b * 4;
        c1 += p[0]; s1 += p[1]; qa += p[2]; q1 += p[3];
    }
    for (int off = 32; off > 0; off >>= 1) {
        c1 += __shfl_down(c1, off, 64);
        s1 += __shfl_down(s1, off, 64);
        qa += __shfl_down(qa, off, 64);
        q1 += __shfl_down(q1, off, 64);
    }
    __shared__ double sm[16][4];
    const int wid  = threadIdx.x >> 6;
    const int lane = threadIdx.x & 63;
    if (lane == 0) {
        sm[wid][0] = c1; sm[wid][1] = s1;
        sm[wid][2] = qa; sm[wid][3] = q1;
    }
    __syncthreads();
    if (threadIdx.x == 0) {
        double a0 = 0, a1 = 0, a2 = 0, a3 = 0;
        const int nw = blockDim.x >> 6;
        for (int w = 0; w < nw; ++w) {
            a0 += sm[w][0]; a1 += sm[w][1];
            a2 += sm[w][2]; a3 += sm[w][3];
        }
        double cc1 = a0;
        double cc0 = (double)n - cc1;
        double w0 = 1.0 / ((cc0 + SMOOTH) * (cc0 + SMOOTH));
        double w1 = 1.0 / ((cc1 + SMOOTH) * (cc1 + SMOOTH));
        double q0 = a2 - a3;               // q_all - q1
        double I  = w1 * a1;
        double D  = w0 * q0 + w1 * (a3 + cc1);  // sum(t*t | t==1) == c1
        out[0] = (float)(1.0 - (2.0 * I + SMOOTH) / (D + SMOOTH));
    }
}

extern "C" void kernel_launch(void* const* d_in, const int* in_sizes, int n_in,
                              void* d_out, int out_size, void* d_ws, size_t ws_size,
                              hipStream_t stream) {
    const float* in = (const float*)d_in[0];
    const int*   tg = (const int*)d_in[1];
    long long n = (long long)in_sizes[0];
    double* ws = (double*)d_ws;

    const int block = 256;
    const int grid  = 2048;  // 8 blocks/CU x 4 waves = 32 waves/CU

    balanced_loss_stage1<<<grid, block, 0, stream>>>(in, tg, n, ws);
    balanced_loss_stage2<<<1, 1024, 0, stream>>>(ws, grid, (float*)d_out, n);
}